// Round 1
// 695.044 us; speedup vs baseline: 1.1904x; 1.1904x over previous
//
#include <hip/hip_runtime.h>
#include <hip/hip_bf16.h>
#include <cstddef>
#include <cstdint>

// Problem constants
#define B_     8
#define N_     1024
#define EMB_   768
#define HEADS_ 12
#define HDIM_  64
#define M_TOK  (B_ * N_)           // 8192
#define QKVF   (3 * EMB_)          // 2304
#define OUT_ELEMS  ((size_t)M_TOK * EMB_)            // 6,291,456
#define ATTN_ELEMS ((size_t)B_ * HEADS_ * N_ * N_)   // 100,663,296

using short8  = __attribute__((ext_vector_type(8))) short;   // 8 bf16 = 4 VGPRs
using floatx4 = __attribute__((ext_vector_type(4))) float;

__device__ __forceinline__ short f32_to_bf16(float f) {
    union { float f; unsigned u; } x; x.f = f;
    unsigned r = x.u + 0x7FFFu + ((x.u >> 16) & 1u);   // RNE
    return (short)(r >> 16);
}

// async global->LDS, 16B per lane; LDS dst = wave-uniform base + lane*16
__device__ __forceinline__ void gload_lds16(const void* g, void* l) {
    __builtin_amdgcn_global_load_lds(
        (const __attribute__((address_space(1))) void*)g,
        (__attribute__((address_space(3))) void*)l, 16, 0, 0);
}

__device__ __forceinline__ floatx4 mfma16(short8 a, short8 b, floatx4 c) {
    return __builtin_amdgcn_mfma_f32_16x16x32_bf16(a, b, c, 0, 0, 0);
}

// ---------------------------------------------------------------------------
// cast fp32 -> bf16, exact grid (n multiple of 1024)
// ---------------------------------------------------------------------------
__global__ __launch_bounds__(256) void cast_kernel(const float* __restrict__ in,
                                                   short* __restrict__ out) {
    const int i = (blockIdx.x * 256 + threadIdx.x) * 4;
    const float4 v = *reinterpret_cast<const float4*>(&in[i]);
    short s0 = f32_to_bf16(v.x), s1 = f32_to_bf16(v.y);
    short s2 = f32_to_bf16(v.z), s3 = f32_to_bf16(v.w);
    using short4v = __attribute__((ext_vector_type(4))) short;
    short4v s = {s0, s1, s2, s3};
    *reinterpret_cast<short4v*>(&out[i]) = s;
}

// ---------------------------------------------------------------------------
// bf16 MFMA GEMM: C[M,N] = A[M,K] * B[N,K]^T + bias  (unchanged, verified)
// ---------------------------------------------------------------------------
template <int OUT_BF16>
__global__ __launch_bounds__(256) void mfma_gemm_bt(
    const short* __restrict__ A, int lda,
    const short* __restrict__ Bm, int ldb,
    const float* __restrict__ bias,
    void* __restrict__ Cp, int ldc, int K)
{
    __shared__ short As[128 * 32];
    __shared__ short Bs[128 * 32];

    const int t = threadIdx.x, lane = t & 63, w = t >> 6;
    const int wy = w >> 1, wx = w & 1;
    const int row0 = blockIdx.y * 128;
    const int col0 = blockIdx.x * 128;
    const int m = lane & 15, kc = lane >> 4;
    const int sw = kc ^ ((m >> 1) & 3);

    floatx4 acc[4][4] = {};

    for (int k0 = 0; k0 < K; k0 += 32) {
        __syncthreads();
#pragma unroll
        for (int p = 0; p < 2; ++p) {
            const int ci = p * 256 + w * 64 + lane;
            const int r = ci >> 2, c = ci & 3;
            const int g = c ^ ((r >> 1) & 3);
            gload_lds16(&A[(size_t)(row0 + r) * lda + k0 + g * 8],
                        &As[(p * 256 + w * 64) * 8]);
            gload_lds16(&Bm[(size_t)(col0 + r) * ldb + k0 + g * 8],
                        &Bs[(p * 256 + w * 64) * 8]);
        }
        __syncthreads();

        short8 af[4], bf[4];
#pragma unroll
        for (int i = 0; i < 4; ++i)
            af[i] = *reinterpret_cast<const short8*>(
                &As[((wy * 64 + i * 16 + m) * 4 + sw) * 8]);
#pragma unroll
        for (int j = 0; j < 4; ++j)
            bf[j] = *reinterpret_cast<const short8*>(
                &Bs[((wx * 64 + j * 16 + m) * 4 + sw) * 8]);
#pragma unroll
        for (int i = 0; i < 4; ++i)
#pragma unroll
            for (int j = 0; j < 4; ++j)
                acc[i][j] = mfma16(af[i], bf[j], acc[i][j]);
    }

    const int rq = lane >> 4;
#pragma unroll
    for (int i = 0; i < 4; ++i) {
        const int rbase = row0 + wy * 64 + i * 16 + rq * 4;
#pragma unroll
        for (int j = 0; j < 4; ++j) {
            const int cc = col0 + wx * 64 + j * 16 + m;
            const float bb = bias[cc];
#pragma unroll
            for (int rg = 0; rg < 4; ++rg) {
                const float v = acc[i][j][rg] + bb;
                if (OUT_BF16)
                    ((short*)Cp)[(size_t)(rbase + rg) * ldc + cc] = f32_to_bf16(v);
                else
                    ((float*)Cp)[(size_t)(rbase + rg) * ldc + cc] = v;
            }
        }
    }
}

// ---------------------------------------------------------------------------
// Transpose V: qkv[b*1024+m][2*768+h*64+d] (bf16) -> Vt[bh][d][m]  (unchanged)
// ---------------------------------------------------------------------------
__global__ __launch_bounds__(256) void transpose_v(
    const short* __restrict__ qkv, short* __restrict__ Vt)
{
    __shared__ short T[64][72];
    const int bh = blockIdx.y, b = bh / HEADS_, h = bh % HEADS_;
    const int m0 = blockIdx.x * 64;
    const int t = threadIdx.x;
    const size_t vbase = (size_t)(b * N_) * QKVF + 2 * EMB_ + h * HDIM_;

#pragma unroll
    for (int p = 0; p < 2; ++p) {
        const int ci = p * 256 + t;          // 0..511
        const int r = ci >> 3, c = ci & 7;   // m-row, d-chunk
        const short8 v = *reinterpret_cast<const short8*>(
            &qkv[vbase + (size_t)(m0 + r) * QKVF + c * 8]);
#pragma unroll
        for (int j = 0; j < 8; ++j) T[c * 8 + j][r] = v[j];
    }
    __syncthreads();
#pragma unroll
    for (int p = 0; p < 2; ++p) {
        const int ci = p * 256 + t;
        const int d = ci >> 3, c = ci & 7;
        short8 v;
#pragma unroll
        for (int j = 0; j < 8; ++j) v[j] = T[d][c * 8 + j];
        *reinterpret_cast<short8*>(&Vt[((size_t)bh * 64 + d) * N_ + m0 + c * 8]) = v;
    }
}

// ---------------------------------------------------------------------------
// Fused attention: scores + softmax + attn@V in one kernel.
// Block = 4 waves, 128 q-rows of one (b,h); m-loop in steps of 64, 2 passes:
//   pass 1: S = Q K^T (MFMA), online per-row max/expsum in registers
//   pass 2: recompute S, P = exp(x-M)/S  -> fp32 attn (nontemporal, write-once)
//           and bf16 -> LDS -> O += P V (MFMA).
// K/V tiles double-buffered (1 barrier/step). attn traffic: 1 write, 0 reads.
// Wave w owns rows [w*32, w*32+32): S wave-tile 32x64 (frags i=2, j=4),
// O wave-tile 32x64 (d), stats reduce via shfl_xor within 16-lane groups.
// ---------------------------------------------------------------------------
__global__ __launch_bounds__(256) void fused_attn(
    const short* __restrict__ qkv, const short* __restrict__ Vt,
    float* __restrict__ attn, short* __restrict__ O)
{
    __shared__ short Qs[128 * 64];       // [row][8 chunks of 8], g = c ^ (r&7)
    __shared__ short Ks[2][64 * 64];     // double-buffered K tile
    __shared__ short Vs[2][64 * 64];     // double-buffered V^T tile [d][m]
    __shared__ short Ps[128 * 72];       // bf16 P tile, padded stride 72
    __shared__ float rowM[128];
    __shared__ float rowS[128];

    const int t = threadIdx.x, lane = t & 63, w = t >> 6;
    const int bh = blockIdx.y, b = bh / HEADS_, h = bh % HEADS_;
    const int n0 = blockIdx.x * 128;
    const int m = lane & 15, kc = lane >> 4;      // kc == rq (C-layout row grp)
    const size_t qbase = (size_t)(b * N_) * QKVF + h * HDIM_;
    const size_t kbase = qbase + EMB_;

#define STAGE_K(buf, k0src)                                                   \
    do {                                                                      \
        _Pragma("unroll")                                                     \
        for (int p = 0; p < 2; ++p) {                                         \
            const int ci = p * 256 + w * 64 + lane;                           \
            const int r = ci >> 3, c = ci & 7;                                \
            const int g = c ^ (r & 7);                                        \
            gload_lds16(&qkv[kbase + (size_t)((k0src) + r) * QKVF + g * 8],   \
                        &Ks[buf][(p * 256 + w * 64) * 8]);                    \
        }                                                                     \
    } while (0)

#define STAGE_V(buf, k0src)                                                   \
    do {                                                                      \
        _Pragma("unroll")                                                     \
        for (int p = 0; p < 2; ++p) {                                         \
            const int ci = p * 256 + w * 64 + lane;                           \
            const int r = ci >> 3, c = ci & 7;                                \
            const int g = c ^ (r & 7);                                        \
            gload_lds16(&Vt[((size_t)bh * 64 + r) * N_ + (k0src) + g * 8],    \
                        &Vs[buf][(p * 256 + w * 64) * 8]);                    \
        }                                                                     \
    } while (0)

    // ---- prologue: stage Q (whole block) + K tile 0 ----
#pragma unroll
    for (int p = 0; p < 4; ++p) {
        const int ci = p * 256 + w * 64 + lane;   // 0..1023
        const int r = ci >> 3, c = ci & 7;
        const int g = c ^ (r & 7);
        gload_lds16(&qkv[qbase + (size_t)(n0 + r) * QKVF + g * 8],
                    &Qs[(p * 256 + w * 64) * 8]);
    }
    STAGE_K(0, 0);
    __syncthreads();

    // hoist Q fragments into registers (used by both passes)
    short8 qf[2][2];
#pragma unroll
    for (int i = 0; i < 2; ++i)
#pragma unroll
        for (int ks = 0; ks < 2; ++ks) {
            const int row = w * 32 + i * 16 + m;          // row&7 == m&7
            const int chunk = ks * 4 + kc;
            qf[i][ks] = *reinterpret_cast<const short8*>(
                &Qs[(row * 8 + (chunk ^ (m & 7))) * 8]);
        }

    // ---- pass 1: online row max / expsum ----
    float m_run[2][4], s_run[2][4];
#pragma unroll
    for (int i = 0; i < 2; ++i)
#pragma unroll
        for (int rg = 0; rg < 4; ++rg) { m_run[i][rg] = -1e30f; s_run[i][rg] = 0.0f; }

    for (int s = 0; s < 16; ++s) {
        const int cur = s & 1;
        if (s < 15) STAGE_K(cur ^ 1, (s + 1) * 64);

        floatx4 acc[2][4] = {};
#pragma unroll
        for (int ks = 0; ks < 2; ++ks) {
            const int chunk = ks * 4 + kc;
            const int pcs = chunk ^ (m & 7);
            short8 bfr[4];
#pragma unroll
            for (int j = 0; j < 4; ++j)
                bfr[j] = *reinterpret_cast<const short8*>(
                    &Ks[cur][((j * 16 + m) * 8 + pcs) * 8]);
#pragma unroll
            for (int i = 0; i < 2; ++i)
#pragma unroll
                for (int j = 0; j < 4; ++j)
                    acc[i][j] = mfma16(qf[i][ks], bfr[j], acc[i][j]);
        }

#pragma unroll
        for (int i = 0; i < 2; ++i)
#pragma unroll
            for (int rg = 0; rg < 4; ++rg) {
                const float x0 = acc[i][0][rg] * 0.125f;
                const float x1 = acc[i][1][rg] * 0.125f;
                const float x2 = acc[i][2][rg] * 0.125f;
                const float x3 = acc[i][3][rg] * 0.125f;
                float tm = fmaxf(fmaxf(x0, x1), fmaxf(x2, x3));
#pragma unroll
                for (int off = 1; off < 16; off <<= 1)
                    tm = fmaxf(tm, __shfl_xor(tm, off));
                const float mn = fmaxf(m_run[i][rg], tm);
                float ts = expf(x0 - mn) + expf(x1 - mn)
                         + expf(x2 - mn) + expf(x3 - mn);
#pragma unroll
                for (int off = 1; off < 16; off <<= 1)
                    ts += __shfl_xor(ts, off);
                s_run[i][rg] = s_run[i][rg] * expf(m_run[i][rg] - mn) + ts;
                m_run[i][rg] = mn;
            }
        __syncthreads();
    }

    // publish row stats (each wave owns its 32 rows; lanes m==0 cover all rq)
    if (m == 0) {
#pragma unroll
        for (int i = 0; i < 2; ++i)
#pragma unroll
            for (int rg = 0; rg < 4; ++rg) {
                const int row = w * 32 + i * 16 + kc * 4 + rg;
                rowM[row] = m_run[i][rg];
                rowS[row] = s_run[i][rg];
            }
    }
    STAGE_K(0, 0);
    STAGE_V(0, 0);
    __syncthreads();

    float Mreg[2][4], Sinv[2][4];
#pragma unroll
    for (int i = 0; i < 2; ++i)
#pragma unroll
        for (int rg = 0; rg < 4; ++rg) {
            const int row = w * 32 + i * 16 + kc * 4 + rg;
            Mreg[i][rg] = rowM[row];
            Sinv[i][rg] = 1.0f / rowS[row];
        }

    // ---- pass 2: recompute S, normalize, write attn, accumulate O ----
    floatx4 accO[2][4] = {};

    for (int s = 0; s < 16; ++s) {
        const int cur = s & 1;
        if (s < 15) { STAGE_K(cur ^ 1, (s + 1) * 64); STAGE_V(cur ^ 1, (s + 1) * 64); }

        floatx4 acc[2][4] = {};
#pragma unroll
        for (int ks = 0; ks < 2; ++ks) {
            const int chunk = ks * 4 + kc;
            const int pcs = chunk ^ (m & 7);
            short8 bfr[4];
#pragma unroll
            for (int j = 0; j < 4; ++j)
                bfr[j] = *reinterpret_cast<const short8*>(
                    &Ks[cur][((j * 16 + m) * 8 + pcs) * 8]);
#pragma unroll
            for (int i = 0; i < 2; ++i)
#pragma unroll
                for (int j = 0; j < 4; ++j)
                    acc[i][j] = mfma16(qf[i][ks], bfr[j], acc[i][j]);
        }

        // normalize + write fp32 attn (nontemporal: never re-read) + bf16 -> Ps
        const int k0 = s * 64;
#pragma unroll
        for (int i = 0; i < 2; ++i)
#pragma unroll
            for (int rg = 0; rg < 4; ++rg) {
                const int row = w * 32 + i * 16 + kc * 4 + rg;
                const float M = Mreg[i][rg], inv = Sinv[i][rg];
                float* dst = &attn[((size_t)bh * N_ + n0 + row) * N_ + k0];
#pragma unroll
                for (int j = 0; j < 4; ++j) {
                    const float p = expf(acc[i][j][rg] * 0.125f - M) * inv;
                    __builtin_nontemporal_store(p, &dst[j * 16 + m]);
                    Ps[row * 72 + j * 16 + m] = f32_to_bf16(p);
                }
            }

        // O += P @ V  (A rows are wave-private: no cross-wave barrier needed)
#pragma unroll
        for (int ks = 0; ks < 2; ++ks) {
            const int chunk = ks * 4 + kc;
            const int pcs = chunk ^ (m & 7);
            short8 pa[2], vb[4];
#pragma unroll
            for (int i = 0; i < 2; ++i)
                pa[i] = *reinterpret_cast<const short8*>(
                    &Ps[(w * 32 + i * 16 + m) * 72 + chunk * 8]);
#pragma unroll
            for (int j = 0; j < 4; ++j)
                vb[j] = *reinterpret_cast<const short8*>(
                    &Vs[cur][((j * 16 + m) * 8 + pcs) * 8]);
#pragma unroll
            for (int i = 0; i < 2; ++i)
#pragma unroll
                for (int j = 0; j < 4; ++j)
                    accO[i][j] = mfma16(pa[i], vb[j], accO[i][j]);
        }
        __syncthreads();
    }

    // ---- epilogue: O -> global bf16 ----
#pragma unroll
    for (int i = 0; i < 2; ++i)
#pragma unroll
        for (int j = 0; j < 4; ++j)
#pragma unroll
            for (int rg = 0; rg < 4; ++rg) {
                const int row = n0 + w * 32 + i * 16 + kc * 4 + rg;
                const int col = h * HDIM_ + j * 16 + m;
                O[(size_t)(b * N_ + row) * EMB_ + col] = f32_to_bf16(accO[i][j][rg]);
            }
#undef STAGE_K
#undef STAGE_V
}

// ---------------------------------------------------------------------------
extern "C" void kernel_launch(void* const* d_in, const int* in_sizes, int n_in,
                              void* d_out, int out_size, void* d_ws, size_t ws_size,
                              hipStream_t stream)
{
    const float* x     = (const float*)d_in[0];
    const float* w_qkv = (const float*)d_in[1];
    const float* b_qkv = (const float*)d_in[2];
    const float* w_out = (const float*)d_in[3];
    const float* b_out = (const float*)d_in[4];

    float* out  = (float*)d_out;
    float* attn = out + OUT_ELEMS;

    // workspace layout (bf16 shorts)
    short* qkvb = (short*)d_ws;                                   // 8192 x 2304
    short* xb   = qkvb + (size_t)M_TOK * QKVF;                    // 8192 x 768
    short* wqb  = xb   + OUT_ELEMS;                               // 2304 x 768
    short* wob  = wqb  + (size_t)QKVF * EMB_;                     // 768 x 768
    short* Vt   = wob  + (size_t)EMB_ * EMB_;                     // 96 x 64 x 1024
    short* O    = Vt   + (size_t)B_ * HEADS_ * HDIM_ * N_;        // 8192 x 768

    const dim3 blk(256);

    // casts
    cast_kernel<<<dim3(OUT_ELEMS / 1024), blk, 0, stream>>>(x, xb);
    cast_kernel<<<dim3((QKVF * EMB_) / 1024), blk, 0, stream>>>(w_qkv, wqb);
    cast_kernel<<<dim3((EMB_ * EMB_) / 1024), blk, 0, stream>>>(w_out, wob);

    // 1. QKV projection (bf16 out)
    mfma_gemm_bt<1><<<dim3(QKVF / 128, M_TOK / 128), blk, 0, stream>>>(
        xb, EMB_, wqb, EMB_, b_qkv, qkvb, QKVF, EMB_);

    // 2. V transpose
    transpose_v<<<dim3(N_ / 64, B_ * HEADS_), blk, 0, stream>>>(qkvb, Vt);

    // 3-5. fused scores + softmax + attn@V (attn written once, fp32)
    fused_attn<<<dim3(N_ / 128, B_ * HEADS_), blk, 0, stream>>>(qkvb, Vt, attn, O);

    // 6. output projection (fp32 out + bias)
    mfma_gemm_bt<0><<<dim3(EMB_ / 128, M_TOK / 128), blk, 0, stream>>>(
        O, EMB_, wob, EMB_, b_out, out, EMB_, EMB_);
}

// Round 2
// 616.976 us; speedup vs baseline: 1.3410x; 1.1265x over previous
//
#include <hip/hip_runtime.h>
#include <hip/hip_bf16.h>
#include <cstddef>
#include <cstdint>

// Problem constants
#define B_     8
#define N_     1024
#define EMB_   768
#define HEADS_ 12
#define HDIM_  64
#define M_TOK  (B_ * N_)           // 8192
#define QKVF   (3 * EMB_)          // 2304
#define OUT_ELEMS  ((size_t)M_TOK * EMB_)            // 6,291,456
#define ATTN_ELEMS ((size_t)B_ * HEADS_ * N_ * N_)   // 100,663,296

// exp(0.125*x) == exp2(x * 0.125*log2(e))
#define CEXP 0.18033688011112042f

using short8  = __attribute__((ext_vector_type(8))) short;   // 8 bf16 = 4 VGPRs
using floatx4 = __attribute__((ext_vector_type(4))) float;

__device__ __forceinline__ short f32_to_bf16(float f) {
    union { float f; unsigned u; } x; x.f = f;
    unsigned r = x.u + 0x7FFFu + ((x.u >> 16) & 1u);   // RNE
    return (short)(r >> 16);
}

// async global->LDS, 16B per lane; LDS dst = wave-uniform base + lane*16
__device__ __forceinline__ void gload_lds16(const void* g, void* l) {
    __builtin_amdgcn_global_load_lds(
        (const __attribute__((address_space(1))) void*)g,
        (__attribute__((address_space(3))) void*)l, 16, 0, 0);
}

__device__ __forceinline__ floatx4 mfma16(short8 a, short8 b, floatx4 c) {
    return __builtin_amdgcn_mfma_f32_16x16x32_bf16(a, b, c, 0, 0, 0);
}

// ---------------------------------------------------------------------------
// cast fp32 -> bf16, exact grid (n multiple of 1024)
// ---------------------------------------------------------------------------
__global__ __launch_bounds__(256) void cast_kernel(const float* __restrict__ in,
                                                   short* __restrict__ out) {
    const int i = (blockIdx.x * 256 + threadIdx.x) * 4;
    const float4 v = *reinterpret_cast<const float4*>(&in[i]);
    short s0 = f32_to_bf16(v.x), s1 = f32_to_bf16(v.y);
    short s2 = f32_to_bf16(v.z), s3 = f32_to_bf16(v.w);
    using short4v = __attribute__((ext_vector_type(4))) short;
    short4v s = {s0, s1, s2, s3};
    *reinterpret_cast<short4v*>(&out[i]) = s;
}

// ---------------------------------------------------------------------------
// bf16 MFMA GEMM: C[M,N] = A[M,K] * B[N,K]^T + bias  (unchanged, verified)
// ---------------------------------------------------------------------------
template <int OUT_BF16>
__global__ __launch_bounds__(256) void mfma_gemm_bt(
    const short* __restrict__ A, int lda,
    const short* __restrict__ Bm, int ldb,
    const float* __restrict__ bias,
    void* __restrict__ Cp, int ldc, int K)
{
    __shared__ short As[128 * 32];
    __shared__ short Bs[128 * 32];

    const int t = threadIdx.x, lane = t & 63, w = t >> 6;
    const int wy = w >> 1, wx = w & 1;
    const int row0 = blockIdx.y * 128;
    const int col0 = blockIdx.x * 128;
    const int m = lane & 15, kc = lane >> 4;
    const int sw = kc ^ ((m >> 1) & 3);

    floatx4 acc[4][4] = {};

    for (int k0 = 0; k0 < K; k0 += 32) {
        __syncthreads();
#pragma unroll
        for (int p = 0; p < 2; ++p) {
            const int ci = p * 256 + w * 64 + lane;
            const int r = ci >> 2, c = ci & 3;
            const int g = c ^ ((r >> 1) & 3);
            gload_lds16(&A[(size_t)(row0 + r) * lda + k0 + g * 8],
                        &As[(p * 256 + w * 64) * 8]);
            gload_lds16(&Bm[(size_t)(col0 + r) * ldb + k0 + g * 8],
                        &Bs[(p * 256 + w * 64) * 8]);
        }
        __syncthreads();

        short8 af[4], bf[4];
#pragma unroll
        for (int i = 0; i < 4; ++i)
            af[i] = *reinterpret_cast<const short8*>(
                &As[((wy * 64 + i * 16 + m) * 4 + sw) * 8]);
#pragma unroll
        for (int j = 0; j < 4; ++j)
            bf[j] = *reinterpret_cast<const short8*>(
                &Bs[((wx * 64 + j * 16 + m) * 4 + sw) * 8]);
#pragma unroll
        for (int i = 0; i < 4; ++i)
#pragma unroll
            for (int j = 0; j < 4; ++j)
                acc[i][j] = mfma16(af[i], bf[j], acc[i][j]);
    }

    const int rq = lane >> 4;
#pragma unroll
    for (int i = 0; i < 4; ++i) {
        const int rbase = row0 + wy * 64 + i * 16 + rq * 4;
#pragma unroll
        for (int j = 0; j < 4; ++j) {
            const int cc = col0 + wx * 64 + j * 16 + m;
            const float bb = bias[cc];
#pragma unroll
            for (int rg = 0; rg < 4; ++rg) {
                const float v = acc[i][j][rg] + bb;
                if (OUT_BF16)
                    ((short*)Cp)[(size_t)(rbase + rg) * ldc + cc] = f32_to_bf16(v);
                else
                    ((float*)Cp)[(size_t)(rbase + rg) * ldc + cc] = v;
            }
        }
    }
}

// ---------------------------------------------------------------------------
// Transpose V: qkv[b*1024+m][2*768+h*64+d] (bf16) -> Vt[bh][d][m]  (unchanged)
// ---------------------------------------------------------------------------
__global__ __launch_bounds__(256) void transpose_v(
    const short* __restrict__ qkv, short* __restrict__ Vt)
{
    __shared__ short T[64][72];
    const int bh = blockIdx.y, b = bh / HEADS_, h = bh % HEADS_;
    const int m0 = blockIdx.x * 64;
    const int t = threadIdx.x;
    const size_t vbase = (size_t)(b * N_) * QKVF + 2 * EMB_ + h * HDIM_;

#pragma unroll
    for (int p = 0; p < 2; ++p) {
        const int ci = p * 256 + t;          // 0..511
        const int r = ci >> 3, c = ci & 7;   // m-row, d-chunk
        const short8 v = *reinterpret_cast<const short8*>(
            &qkv[vbase + (size_t)(m0 + r) * QKVF + c * 8]);
#pragma unroll
        for (int j = 0; j < 8; ++j) T[c * 8 + j][r] = v[j];
    }
    __syncthreads();
#pragma unroll
    for (int p = 0; p < 2; ++p) {
        const int ci = p * 256 + t;
        const int d = ci >> 3, c = ci & 7;
        short8 v;
#pragma unroll
        for (int j = 0; j < 8; ++j) v[j] = T[d][c * 8 + j];
        *reinterpret_cast<short8*>(&Vt[((size_t)bh * 64 + d) * N_ + m0 + c * 8]) = v;
    }
}

// ---------------------------------------------------------------------------
// Fused attention: scores + softmax + attn@V in one kernel.
// Block = 4 waves, 128 q-rows of one (b,h); m-loop in steps of 64, 2 passes:
//   pass 1: S = Q K^T (MFMA), PER-LANE online max/expsum (no in-loop shfl;
//           one 16-lane shfl reduce after the loop -> each lane owns its row)
//   pass 2: recompute S, P = exp2((x-M)*C)/S -> fp32 attn (write-once) and
//           bf16 -> LDS (reusing the dead Q buffer, XOR-swizzled) -> O += P V.
// LDS = 48KB -> 3 blocks/CU (vs 68.6KB / 2 before).
// Grid is (bh, n-block) so all n-blocks of one head share an XCD L2
// (96 % 8 == 0 -> xcd = bh % 8): K/V hot set 3MB < 4MB per-XCD L2.
// ---------------------------------------------------------------------------
__global__ __launch_bounds__(256) void fused_attn(
    const short* __restrict__ qkv, const short* __restrict__ Vt,
    float* __restrict__ attn, short* __restrict__ O)
{
    __shared__ short QP[128 * 64];       // Q (prologue) then P bf16 (pass 2)
    __shared__ short Ks[2][64 * 64];     // double-buffered K tile
    __shared__ short Vs[2][64 * 64];     // double-buffered V^T tile [d][m]

    const int t = threadIdx.x, lane = t & 63, w = t >> 6;
    const int bh = blockIdx.x, b = bh / HEADS_, h = bh % HEADS_;
    const int n0 = blockIdx.y * 128;
    const int m = lane & 15, kc = lane >> 4;      // kc == C-layout row group
    const size_t qbase = (size_t)(b * N_) * QKVF + h * HDIM_;
    const size_t kbase = qbase + EMB_;

#define STAGE_K(buf, k0src)                                                   \
    do {                                                                      \
        _Pragma("unroll")                                                     \
        for (int p = 0; p < 2; ++p) {                                         \
            const int ci = p * 256 + w * 64 + lane;                           \
            const int r = ci >> 3, c = ci & 7;                                \
            const int g = c ^ (r & 7);                                        \
            gload_lds16(&qkv[kbase + (size_t)((k0src) + r) * QKVF + g * 8],   \
                        &Ks[buf][(p * 256 + w * 64) * 8]);                    \
        }                                                                     \
    } while (0)

#define STAGE_V(buf, k0src)                                                   \
    do {                                                                      \
        _Pragma("unroll")                                                     \
        for (int p = 0; p < 2; ++p) {                                         \
            const int ci = p * 256 + w * 64 + lane;                           \
            const int r = ci >> 3, c = ci & 7;                                \
            const int g = c ^ (r & 7);                                        \
            gload_lds16(&Vt[((size_t)bh * 64 + r) * N_ + (k0src) + g * 8],    \
                        &Vs[buf][(p * 256 + w * 64) * 8]);                    \
        }                                                                     \
    } while (0)

    // ---- prologue: stage Q (whole block) + K tile 0 ----
#pragma unroll
    for (int p = 0; p < 4; ++p) {
        const int ci = p * 256 + w * 64 + lane;   // 0..1023
        const int r = ci >> 3, c = ci & 7;
        const int g = c ^ (r & 7);
        gload_lds16(&qkv[qbase + (size_t)(n0 + r) * QKVF + g * 8],
                    &QP[(p * 256 + w * 64) * 8]);
    }
    STAGE_K(0, 0);
    __syncthreads();

    // hoist Q fragments into registers (QP is dead for Q after this)
    short8 qf[2][2];
#pragma unroll
    for (int i = 0; i < 2; ++i)
#pragma unroll
        for (int ks = 0; ks < 2; ++ks) {
            const int row = w * 32 + i * 16 + m;          // row&7 == m&7
            const int chunk = ks * 4 + kc;
            qf[i][ks] = *reinterpret_cast<const short8*>(
                &QP[(row * 8 + (chunk ^ (m & 7))) * 8]);
        }

    // ---- pass 1: per-lane online row max / expsum (no in-loop shfl) ----
    float m_run[2][4], s_run[2][4];
#pragma unroll
    for (int i = 0; i < 2; ++i)
#pragma unroll
        for (int rg = 0; rg < 4; ++rg) { m_run[i][rg] = -1e30f; s_run[i][rg] = 0.0f; }

    for (int s = 0; s < 16; ++s) {
        const int cur = s & 1;
        if (s < 15) STAGE_K(cur ^ 1, (s + 1) * 64);

        floatx4 acc[2][4] = {};
#pragma unroll
        for (int ks = 0; ks < 2; ++ks) {
            const int chunk = ks * 4 + kc;
            const int pcs = chunk ^ (m & 7);
            short8 bfr[4];
#pragma unroll
            for (int j = 0; j < 4; ++j)
                bfr[j] = *reinterpret_cast<const short8*>(
                    &Ks[cur][((j * 16 + m) * 8 + pcs) * 8]);
#pragma unroll
            for (int i = 0; i < 2; ++i)
#pragma unroll
                for (int j = 0; j < 4; ++j)
                    acc[i][j] = mfma16(qf[i][ks], bfr[j], acc[i][j]);
        }

#pragma unroll
        for (int i = 0; i < 2; ++i)
#pragma unroll
            for (int rg = 0; rg < 4; ++rg) {
                const float x0 = acc[i][0][rg], x1 = acc[i][1][rg];
                const float x2 = acc[i][2][rg], x3 = acc[i][3][rg];
                const float tm = fmaxf(fmaxf(x0, x1), fmaxf(x2, x3));
                const float mo = m_run[i][rg];
                const float mn = fmaxf(mo, tm);
                const float f  = exp2f((mo - mn) * CEXP);
                const float ts = exp2f((x0 - mn) * CEXP) + exp2f((x1 - mn) * CEXP)
                               + exp2f((x2 - mn) * CEXP) + exp2f((x3 - mn) * CEXP);
                s_run[i][rg] = s_run[i][rg] * f + ts;
                m_run[i][rg] = mn;
            }
        __syncthreads();
    }

    // one-time 16-lane reduce: each lane ends with M, 1/S of ITS OWN row
    float Mreg[2][4], Sinv[2][4];
#pragma unroll
    for (int i = 0; i < 2; ++i)
#pragma unroll
        for (int rg = 0; rg < 4; ++rg) {
            float M = m_run[i][rg];
#pragma unroll
            for (int off = 1; off < 16; off <<= 1)
                M = fmaxf(M, __shfl_xor(M, off));
            float sc = s_run[i][rg] * exp2f((m_run[i][rg] - M) * CEXP);
#pragma unroll
            for (int off = 1; off < 16; off <<= 1)
                sc += __shfl_xor(sc, off);
            Mreg[i][rg] = M;
            Sinv[i][rg] = 1.0f / sc;
        }

    STAGE_K(0, 0);
    STAGE_V(0, 0);
    __syncthreads();

    // ---- pass 2: recompute S, normalize, write attn, accumulate O ----
    floatx4 accO[2][4] = {};

    for (int s = 0; s < 16; ++s) {
        const int cur = s & 1;
        if (s < 15) { STAGE_K(cur ^ 1, (s + 1) * 64); STAGE_V(cur ^ 1, (s + 1) * 64); }

        floatx4 acc[2][4] = {};
#pragma unroll
        for (int ks = 0; ks < 2; ++ks) {
            const int chunk = ks * 4 + kc;
            const int pcs = chunk ^ (m & 7);
            short8 bfr[4];
#pragma unroll
            for (int j = 0; j < 4; ++j)
                bfr[j] = *reinterpret_cast<const short8*>(
                    &Ks[cur][((j * 16 + m) * 8 + pcs) * 8]);
#pragma unroll
            for (int i = 0; i < 2; ++i)
#pragma unroll
                for (int j = 0; j < 4; ++j)
                    acc[i][j] = mfma16(qf[i][ks], bfr[j], acc[i][j]);
        }

        // normalize + write fp32 attn (write-once) + bf16 -> QP (swizzled)
        const int k0 = s * 64;
#pragma unroll
        for (int i = 0; i < 2; ++i)
#pragma unroll
            for (int rg = 0; rg < 4; ++rg) {
                const int row = w * 32 + i * 16 + kc * 4 + rg;
                const float M = Mreg[i][rg], inv = Sinv[i][rg];
                const int r7 = row & 7;
                float* dst = &attn[((size_t)bh * N_ + n0 + row) * N_ + k0];
#pragma unroll
                for (int j = 0; j < 4; ++j) {
                    const float p = exp2f((acc[i][j][rg] - M) * CEXP) * inv;
                    dst[j * 16 + m] = p;
                    const int col = j * 16 + m;
                    const int pc = (col >> 3) ^ r7;
                    QP[row * 64 + pc * 8 + (col & 7)] = f32_to_bf16(p);
                }
            }

        // O += P @ V  (P rows are wave-private: no cross-wave barrier needed)
#pragma unroll
        for (int ks = 0; ks < 2; ++ks) {
            const int chunk = ks * 4 + kc;
            const int pcs = chunk ^ (m & 7);
            short8 pa[2], vb[4];
#pragma unroll
            for (int i = 0; i < 2; ++i) {
                const int ra = w * 32 + i * 16 + m;       // ra&7 == m&7
                pa[i] = *reinterpret_cast<const short8*>(
                    &QP[(ra * 8 + pcs) * 8]);
            }
#pragma unroll
            for (int j = 0; j < 4; ++j)
                vb[j] = *reinterpret_cast<const short8*>(
                    &Vs[cur][((j * 16 + m) * 8 + pcs) * 8]);
#pragma unroll
            for (int i = 0; i < 2; ++i)
#pragma unroll
                for (int j = 0; j < 4; ++j)
                    accO[i][j] = mfma16(pa[i], vb[j], accO[i][j]);
        }
        __syncthreads();
    }

    // ---- epilogue: O -> global bf16 ----
#pragma unroll
    for (int i = 0; i < 2; ++i)
#pragma unroll
        for (int j = 0; j < 4; ++j)
#pragma unroll
            for (int rg = 0; rg < 4; ++rg) {
                const int row = n0 + w * 32 + i * 16 + kc * 4 + rg;
                const int col = h * HDIM_ + j * 16 + m;
                O[(size_t)(b * N_ + row) * EMB_ + col] = f32_to_bf16(accO[i][j][rg]);
            }
#undef STAGE_K
#undef STAGE_V
}

// ---------------------------------------------------------------------------
extern "C" void kernel_launch(void* const* d_in, const int* in_sizes, int n_in,
                              void* d_out, int out_size, void* d_ws, size_t ws_size,
                              hipStream_t stream)
{
    const float* x     = (const float*)d_in[0];
    const float* w_qkv = (const float*)d_in[1];
    const float* b_qkv = (const float*)d_in[2];
    const float* w_out = (const float*)d_in[3];
    const float* b_out = (const float*)d_in[4];

    float* out  = (float*)d_out;
    float* attn = out + OUT_ELEMS;

    // workspace layout (bf16 shorts)
    short* qkvb = (short*)d_ws;                                   // 8192 x 2304
    short* xb   = qkvb + (size_t)M_TOK * QKVF;                    // 8192 x 768
    short* wqb  = xb   + OUT_ELEMS;                               // 2304 x 768
    short* wob  = wqb  + (size_t)QKVF * EMB_;                     // 768 x 768
    short* Vt   = wob  + (size_t)EMB_ * EMB_;                     // 96 x 64 x 1024
    short* O    = Vt   + (size_t)B_ * HEADS_ * HDIM_ * N_;        // 8192 x 768

    const dim3 blk(256);

    // casts
    cast_kernel<<<dim3(OUT_ELEMS / 1024), blk, 0, stream>>>(x, xb);
    cast_kernel<<<dim3((QKVF * EMB_) / 1024), blk, 0, stream>>>(w_qkv, wqb);
    cast_kernel<<<dim3((EMB_ * EMB_) / 1024), blk, 0, stream>>>(w_out, wob);

    // 1. QKV projection (bf16 out)
    mfma_gemm_bt<1><<<dim3(QKVF / 128, M_TOK / 128), blk, 0, stream>>>(
        xb, EMB_, wqb, EMB_, b_qkv, qkvb, QKVF, EMB_);

    // 2. V transpose
    transpose_v<<<dim3(N_ / 64, B_ * HEADS_), blk, 0, stream>>>(qkvb, Vt);

    // 3-5. fused scores + softmax + attn@V (attn written once, fp32)
    //      grid: x = head (XCD-local n-blocks), y = n-block
    fused_attn<<<dim3(B_ * HEADS_, N_ / 128), blk, 0, stream>>>(qkvb, Vt, attn, O);

    // 6. output projection (fp32 out + bias)
    mfma_gemm_bt<0><<<dim3(EMB_ / 128, M_TOK / 128), blk, 0, stream>>>(
        O, EMB_, wob, EMB_, b_out, out, EMB_, EMB_);
}